// Round 17
// baseline (461.868 us; speedup 1.0000x reference)
//
#include <hip/hip_runtime.h>
#include <hip/hip_bf16.h>
#include <cstdint>
#include <cstddef>

#define B_ 16
#define T_ 2048
#define C_ 1024
#define H_ 256
#define KVB 32

typedef __attribute__((ext_vector_type(8))) short short8;
typedef __attribute__((ext_vector_type(4))) float f32x4;

// fp32 -> bf16 (RNE)
__device__ inline unsigned short f2bf(float f) {
    unsigned int u = __builtin_bit_cast(unsigned int, f);
    unsigned int r = (u + 0x7FFFu + ((u >> 16) & 1u)) >> 16;
    return (unsigned short)r;
}

// async global->LDS, 16B/lane; LDS dest wave-uniform base (+lane*16 by HW)
__device__ inline void glds16(const void* g, void* l) {
    __builtin_amdgcn_global_load_lds(
        (const __attribute__((address_space(1))) unsigned int*)g,
        (__attribute__((address_space(3))) unsigned int*)l, 16, 0, 0);
}

// ---------------------------------------------------------------------------
// Kernel 0: x fp32 -> bf16 (RNE)
// ---------------------------------------------------------------------------
__global__ __launch_bounds__(256) void xconv(const float* __restrict__ x,
                                             unsigned short* __restrict__ xb) {
    const int stride = gridDim.x * 256;
    const int n8 = B_ * T_ * C_ / 8;
    for (int i = blockIdx.x * 256 + threadIdx.x; i < n8; i += stride) {
        f32x4 v0 = *(const f32x4*)(x + (size_t)i * 8);
        f32x4 v1 = *(const f32x4*)(x + (size_t)i * 8 + 4);
        short8 o;
#pragma unroll
        for (int e = 0; e < 4; ++e) {
            o[e] = (short)f2bf(v0[e]);
            o[e + 4] = (short)f2bf(v1[e]);
        }
        *(short8*)(xb + (size_t)i * 8) = o;
    }
}

// ---------------------------------------------------------------------------
// Kernel 1: W [K][N] fp32 -> Wt [mat][N][K] bf16
// ---------------------------------------------------------------------------
__global__ void wconv(const float* __restrict__ Wq, const float* __restrict__ Wk,
                      const float* __restrict__ Wv, unsigned short* __restrict__ Wt) {
    int idx = blockIdx.x * 256 + threadIdx.x;
    const int per = C_ * H_;
    if (idx >= 3 * per) return;
    int mat = idx / per;
    int rem = idx - mat * per;
    int n = rem / C_;
    int k = rem - n * C_;
    const float* W = (mat == 0) ? Wq : (mat == 1) ? Wk : Wv;
    Wt[idx] = f2bf(W[(size_t)k * H_ + n]);
}

// ---------------------------------------------------------------------------
// Kernel 2: QKV GEMM, tail-free phase-packed. Grid = 512 blocks x 512 thr;
// block bx runs 3 phases: (64 x-rows [bx*64, bx*64+64)) x 256 cols for
// mat = 0,1,2 (A rows L2-hot after phase 0). 8 waves = 2r x 4c; wave =
// 32r x 64c, acc[2][4] (32 AGPR). W chunk [256n][64k] staged via swizzled
// glds16, dbuf (64KB LDS). All 512 blocks identical length -> 16 waves/CU
// flat, zero tail.
// ---------------------------------------------------------------------------
__global__ __launch_bounds__(512, 4) void qkv_gemm(
    const unsigned short* __restrict__ xb, const unsigned short* __restrict__ Wt,
    const float* __restrict__ bq, const float* __restrict__ bk,
    const float* __restrict__ bv,
    unsigned short* __restrict__ Qb, unsigned short* __restrict__ Kb,
    unsigned short* __restrict__ Vt)
{
    const int bx = blockIdx.x;                 // 0..511
    const int tid = threadIdx.x;
    const int wid = tid >> 6;
    const int lane = tid & 63;
    const int c16 = lane & 15;
    const int g = lane >> 4;
    const int wr = wid >> 2, wc = wid & 3;
    const int rw = bx * 64 + wr * 32;

    __shared__ __align__(16) unsigned short Wl[2][256 * 64];   // 2 x 32KB

    const unsigned short* xp0 = xb + (size_t)(rw + c16) * C_ + g * 8;
    const unsigned short* xp1 = xb + (size_t)(rw + 16 + c16) * C_ + g * 8;

#define STAGEW(ch, buf)                                                         \
    {                                                                           \
        _Pragma("unroll")                                                       \
        for (int j = 0; j < 4; ++j) {                                           \
            int off = j * 8192 + wid * 1024 + lane * 16;                        \
            int row = off >> 7, colb = off & 127;                               \
            glds16(wbB + (size_t)row * 2048 + (ch) * 128 + (colb ^ ((row & 7) << 4)), \
                   (char*)&Wl[buf][0] + j * 8192 + wid * 1024);                 \
        }                                                                       \
    }

#pragma unroll 1
    for (int mat = 0; mat < 3; ++mat) {
        const char* wbB = (const char*)(Wt + (size_t)mat * H_ * C_);

        f32x4 acc[2][4];
#pragma unroll
        for (int rs = 0; rs < 2; ++rs)
#pragma unroll
            for (int nt = 0; nt < 4; ++nt) acc[rs][nt] = f32x4{0.f, 0.f, 0.f, 0.f};

        STAGEW(0, 0);
        short8 xr0[2], xr1[2];
        xr0[0] = *(const short8*)(xp0);       xr0[1] = *(const short8*)(xp0 + 32);
        xr1[0] = *(const short8*)(xp1);       xr1[1] = *(const short8*)(xp1 + 32);
        __syncthreads();

        for (int ch = 0; ch < 16; ++ch) {
            const int cur = ch & 1;
            short8 af0[2] = {xr0[0], xr0[1]};
            short8 af1[2] = {xr1[0], xr1[1]};
            if (ch < 15) {
                xr0[0] = *(const short8*)(xp0 + (ch + 1) * 64);
                xr0[1] = *(const short8*)(xp0 + (ch + 1) * 64 + 32);
                xr1[0] = *(const short8*)(xp1 + (ch + 1) * 64);
                xr1[1] = *(const short8*)(xp1 + (ch + 1) * 64 + 32);
                STAGEW(ch + 1, cur ^ 1);
            }
#pragma unroll
            for (int kk = 0; kk < 2; ++kk)
#pragma unroll
                for (int nt = 0; nt < 4; ++nt) {
                    const int n = wc * 64 + nt * 16 + c16;
                    short8 bfr = *(const short8*)((const char*)&Wl[cur][0] + n * 128 +
                                                  ((kk * 64 + g * 16) ^ ((n & 7) << 4)));
                    acc[0][nt] = __builtin_amdgcn_mfma_f32_16x16x32_bf16(af0[kk], bfr,
                                                                         acc[0][nt], 0, 0, 0);
                    acc[1][nt] = __builtin_amdgcn_mfma_f32_16x16x32_bf16(af1[kk], bfr,
                                                                         acc[1][nt], 0, 0, 0);
                }
            __syncthreads();   // drains glds(ch+1), guards dbuf swap
        }

        const float* bias = (mat == 0) ? bq : (mat == 1) ? bk : bv;
#pragma unroll
        for (int rs = 0; rs < 2; ++rs)
#pragma unroll
            for (int nt = 0; nt < 4; ++nt) {
                const int n = wc * 64 + nt * 16 + c16;
                const float bias_v = bias[n];
#pragma unroll
                for (int rr = 0; rr < 4; ++rr) {
                    const int rg = rw + rs * 16 + g * 4 + rr;
                    const unsigned short hv = f2bf(acc[rs][nt][rr] + bias_v);
                    if (mat == 0)      Qb[(size_t)rg * H_ + n] = hv;
                    else if (mat == 1) Kb[(size_t)rg * H_ + n] = hv;
                    else {
                        const int bb = rg >> 11, tt = rg & (T_ - 1);
                        Vt[((size_t)bb * H_ + n) * T_ + tt] = hv;
                    }
                }
            }
        __syncthreads();   // all waves done with Wl before next phase restages
    }
#undef STAGEW
}

// ---------------------------------------------------------------------------
// stage one KV tile, split across 4 waves (each stages 4KB of K + 4KB of V):
// K [32kv][256h] XOR-swz; V [256h][32kv] chunk-XOR-swz.
// ---------------------------------------------------------------------------
__device__ inline void stage_tile4(const char* kbB, const char* vtB, int sk,
                                   unsigned short* Kdst, unsigned short* Vdst,
                                   int wid, int lane) {
#pragma unroll
    for (int j = 0; j < 4; ++j) {
        int off = wid * 4096 + j * 1024 + lane * 16;
        int row = off >> 9, colb = off & 511;
        glds16(kbB + (size_t)(sk + row) * 512 + (colb ^ ((row & 7) << 4)),
               (char*)Kdst + off - lane * 16);
    }
#pragma unroll
    for (int j = 0; j < 4; ++j) {
        int off = wid * 4096 + j * 1024 + lane * 16;
        int h = off >> 6;                 // 64B per h-row
        int slot = lane & 3;
        int c = slot ^ ((h >> 1) & 3);    // logical kv-chunk at this slot
        glds16(vtB + (size_t)h * 4096 + (size_t)(sk + c * 8) * 2,
               (char*)Vdst + off - lane * 16);
    }
}

// ---------------------------------------------------------------------------
// Kernel 3: flash attention, kv-split with EXACT-LENGTH PAIRING (R16-proven).
// Block = 4 waves x 16 q = 64 q; every block runs exactly 33 kv-tiles.
// Grid 512 x 256 thr, dbuf K+V -> 2 blocks/CU = 8 waves/CU constant.
// ---------------------------------------------------------------------------
__global__ __launch_bounds__(256) void attn(
    const unsigned short* __restrict__ Qb, const unsigned short* __restrict__ Kb,
    const unsigned short* __restrict__ Vt, float* __restrict__ Opart,
    float2* __restrict__ ml)
{
    const int bx = blockIdx.x;                 // 0..511
    const int b = bx & 15;
    const int ab = (bx >> 4) & 1;              // 0 = A, 1 = B
    const int p = bx >> 5;                     // 0..15
    int qt[2], ts[2], te[2];
    if (ab == 0) {
        qt[0] = p;        ts[0] = 0;          te[0] = p + 1;
        qt[1] = 31 - p;   ts[1] = 32 - p;     te[1] = 64 - 2 * p;
    } else {
        qt[0] = 31 - p;   ts[0] = 0;          te[0] = 32 - p;
        qt[1] = p;        ts[1] = p + 1;      te[1] = 2 * p + 2;
    }
    const int tid = threadIdx.x;
    const int wid = tid >> 6;                  // 0..3
    const int lane = tid & 63;
    const int c16 = lane & 15;
    const int g = lane >> 4;
    const int hsw = (c16 >> 1) & 3;

    __shared__ __align__(16) unsigned short Kl[2][KVB * 256];   // 2 x 16KB
    __shared__ __align__(16) unsigned short Vl[2][256 * KVB];   // 2 x 16KB
    __shared__ __align__(16) unsigned short Pl[4][16 * 32];     // 4KB

    const char* kbB = (const char*)(Kb + (size_t)b * T_ * H_);
    const char* vtB = (const char*)(Vt + (size_t)b * H_ * T_);
    const float inv_scale = 0.022097086912079608f;   // 1/sqrt(2048)

#pragma unroll 1
    for (int ph = 0; ph < 2; ++ph) {
        const int qw = qt[ph] * 64 + wid * 16;
        const int qg = qw + c16;               // this lane's q row

        // Q fragments (B-operand of swapped QK^T)
        short8 qf[8];
        const unsigned short* qp = Qb + (size_t)(b * T_ + qg) * H_ + g * 8;
#pragma unroll
        for (int kc = 0; kc < 8; ++kc) qf[kc] = *(const short8*)(qp + kc * 32);

        f32x4 o[16];
#pragma unroll
        for (int i = 0; i < 16; ++i) o[i] = f32x4{0.f, 0.f, 0.f, 0.f};
        float m = -1e30f, ll = 0.f;

        stage_tile4(kbB, vtB, ts[ph] * KVB, &Kl[0][0], &Vl[0][0], wid, lane);
        __syncthreads();

        for (int t = ts[ph]; t < te[ph]; ++t) {
            const int cur = (t - ts[ph]) & 1;
            const int sk = t * KVB;

            if (t + 1 < te[ph])
                stage_tile4(kbB, vtB, sk + KVB, &Kl[cur ^ 1][0], &Vl[cur ^ 1][0],
                            wid, lane);

            if (sk <= qw + 15) {   // wave-uniform: skip fully-masked tiles
                // ---- S^T = K Q^T : lane holds S[q=qg][kv=sk+ct*16+g*4+rr] ----
                f32x4 sc[2];
                __builtin_amdgcn_s_setprio(1);
#pragma unroll
                for (int ct = 0; ct < 2; ++ct) {
                    f32x4 sa = f32x4{0.f, 0.f, 0.f, 0.f};
                    const int row = ct * 16 + c16;
#pragma unroll
                    for (int kc = 0; kc < 8; ++kc) {
                        short8 kf = *(const short8*)((const char*)&Kl[cur][0] + row * 512 +
                                                     ((kc * 64 + g * 16) ^ ((row & 7) << 4)));
                        sa = __builtin_amdgcn_mfma_f32_16x16x32_bf16(kf, qf[kc], sa, 0, 0, 0);
                    }
                    sc[ct] = sa;
                }
                __builtin_amdgcn_s_setprio(0);

                // ---- mask + scale ----
                float pv[8];
#pragma unroll
                for (int ct = 0; ct < 2; ++ct)
#pragma unroll
                    for (int rr = 0; rr < 4; ++rr) {
                        const int kv = sk + ct * 16 + g * 4 + rr;
                        float v = sc[ct][rr] * inv_scale;
                        pv[ct * 4 + rr] = (kv > qg) ? -1e30f : v;
                    }

                // ---- per-lane softmax (2 cross-lane ops) ----
                float pmax = fmaxf(fmaxf(fmaxf(pv[0], pv[1]), fmaxf(pv[2], pv[3])),
                                   fmaxf(fmaxf(pv[4], pv[5]), fmaxf(pv[6], pv[7])));
                pmax = fmaxf(pmax, __shfl_xor(pmax, 16, 64));
                pmax = fmaxf(pmax, __shfl_xor(pmax, 32, 64));
                if (!__all(pmax <= m + 8.f)) {       // T13 defer-max
                    const float nm = fmaxf(m, pmax);
                    const float scf = __expf(m - nm);
                    ll *= scf;
#pragma unroll
                    for (int mt = 0; mt < 16; ++mt) {
                        o[mt][0] *= scf; o[mt][1] *= scf;
                        o[mt][2] *= scf; o[mt][3] *= scf;
                    }
                    m = nm;
                }
                float rsum = 0.f;
#pragma unroll
                for (int i = 0; i < 8; ++i) { pv[i] = __expf(pv[i] - m); rsum += pv[i]; }
                rsum += __shfl_xor(rsum, 16, 64);
                rsum += __shfl_xor(rsum, 32, 64);
                ll += rsum;

                // ---- P -> bf16 -> wave-local swizzled LDS (4 b32 writes) ----
                unsigned int* pw = (unsigned int*)&Pl[wid][0];
#pragma unroll
                for (int ct = 0; ct < 2; ++ct)
#pragma unroll
                    for (int pr = 0; pr < 2; ++pr) {
                        int w = (ct * 8 + g * 2 + pr) ^ (hsw << 2);
                        unsigned int v = (unsigned int)f2bf(pv[ct * 4 + pr * 2]) |
                                         ((unsigned int)f2bf(pv[ct * 4 + pr * 2 + 1]) << 16);
                        pw[c16 * 16 + w] = v;
                    }
                asm volatile("s_waitcnt lgkmcnt(0)" ::: "memory");
                __builtin_amdgcn_sched_barrier(0);
                short8 pb = *(const short8*)((const char*)&Pl[wid][0] + c16 * 64 +
                                             ((g ^ hsw) << 4));

                // ---- O^T += V^T P^T ----
                __builtin_amdgcn_s_setprio(1);
#pragma unroll
                for (int mt = 0; mt < 16; ++mt) {
                    short8 vf = *(const short8*)((const char*)&Vl[cur][0] +
                                                 (mt * 16 + c16) * 64 + ((g ^ hsw) << 4));
                    o[mt] = __builtin_amdgcn_mfma_f32_16x16x32_bf16(vf, pb, o[mt], 0, 0, 0);
                }
                __builtin_amdgcn_s_setprio(0);
            }

            __syncthreads();   // drains (t+1) glds; guards dbuf + Pl reuse
        }

        // ---- epilogue: raw partials, slot = ph ----
        float* op = Opart + ((size_t)(ph * 16 + b) * T_ + qg) * H_;
#pragma unroll
        for (int mt = 0; mt < 16; ++mt)
            *(f32x4*)(op + mt * 16 + g * 4) = o[mt];
        if (g == 0)
            ml[(size_t)(ph * 16 + b) * T_ + qg] = make_float2(m, ll);
    }
}

// ---------------------------------------------------------------------------
// Kernel 4: combine the two kv-halves per q-row (flash merge).
// ---------------------------------------------------------------------------
__global__ __launch_bounds__(256) void combine(const float* __restrict__ Opart,
                                               const float2* __restrict__ ml,
                                               float* __restrict__ out) {
    const int stride = gridDim.x * 256;
    const int n4 = B_ * T_ * (H_ / 4);
    for (int u = blockIdx.x * 256 + threadIdx.x; u < n4; u += stride) {
        const int row = u >> 6;
        const int c4 = (u & 63) << 2;
        const float2 a = ml[row];
        const float2 bb = ml[B_ * T_ + row];
        const float mx = fmaxf(a.x, bb.x);
        const float w0 = __expf(a.x - mx);
        const float w1 = __expf(bb.x - mx);
        const float inv = 1.f / (a.y * w0 + bb.y * w1);
        f32x4 o0 = *(const f32x4*)(Opart + (size_t)row * H_ + c4);
        f32x4 o1 = *(const f32x4*)(Opart + (size_t)(B_ * T_) * H_ +
                                   (size_t)row * H_ + c4);
        f32x4 ov;
#pragma unroll
        for (int e = 0; e < 4; ++e) ov[e] = (o0[e] * w0 + o1[e] * w1) * inv;
        *(f32x4*)(out + (size_t)row * H_ + c4) = ov;
    }
}

// ---------------------------------------------------------------------------
extern "C" void kernel_launch(void* const* d_in, const int* in_sizes, int n_in,
                              void* d_out, int out_size, void* d_ws, size_t ws_size,
                              hipStream_t stream) {
    const float* x  = (const float*)d_in[0];
    const float* Wq = (const float*)d_in[1];
    const float* bq = (const float*)d_in[2];
    const float* Wk = (const float*)d_in[3];
    const float* bk = (const float*)d_in[4];
    const float* Wv = (const float*)d_in[5];
    const float* bv = (const float*)d_in[6];
    float* out = (float*)d_out;

    char* ws = (char*)d_ws;
    unsigned short* Wt = (unsigned short*)ws;                    // 1.5 MiB @0
    float2* ml         = (float2*)(ws + 1536u * 1024u);          // 512 KiB @1.5M
    unsigned short* Qb = (unsigned short*)(ws + (2u  << 20));    // 16 MiB
    unsigned short* Kb = (unsigned short*)(ws + (18u << 20));    // 16 MiB
    unsigned short* Vt = (unsigned short*)(ws + (34u << 20));    // 16 MiB
    unsigned short* xb = (unsigned short*)(ws + (50u << 20));    // 64 MiB
    float* Opart       = (float*)(ws + (50u << 20));             // reuses xb (dead after qkv)

    hipLaunchKernelGGL(xconv, dim3(2048), dim3(256), 0, stream, x, xb);
    hipLaunchKernelGGL(wconv, dim3((3 * C_ * H_ + 255) / 256), dim3(256), 0, stream,
                       Wq, Wk, Wv, Wt);
    hipLaunchKernelGGL(qkv_gemm, dim3(512), dim3(512), 0, stream,
                       xb, Wt, bq, bk, bv, Qb, Kb, Vt);
    hipLaunchKernelGGL(attn, dim3(512), dim3(256), 0, stream,
                       Qb, Kb, Vt, Opart, ml);
    hipLaunchKernelGGL(combine, dim3(2048), dim3(256), 0, stream,
                       Opart, ml, out);
}

// Round 18
// 275.374 us; speedup vs baseline: 1.6772x; 1.6772x over previous
//
#include <hip/hip_runtime.h>
#include <hip/hip_bf16.h>
#include <cstdint>
#include <cstddef>

#define B_ 16
#define T_ 2048
#define C_ 1024
#define H_ 256
#define KVB 32

typedef __attribute__((ext_vector_type(8))) short short8;
typedef __attribute__((ext_vector_type(4))) float f32x4;

// fp32 -> bf16 (RNE)
__device__ inline unsigned short f2bf(float f) {
    unsigned int u = __builtin_bit_cast(unsigned int, f);
    unsigned int r = (u + 0x7FFFu + ((u >> 16) & 1u)) >> 16;
    return (unsigned short)r;
}

// async global->LDS, 16B/lane; LDS dest wave-uniform base (+lane*16 by HW)
__device__ inline void glds16(const void* g, void* l) {
    __builtin_amdgcn_global_load_lds(
        (const __attribute__((address_space(1))) unsigned int*)g,
        (__attribute__((address_space(3))) unsigned int*)l, 16, 0, 0);
}

// ---------------------------------------------------------------------------
// Kernel 0: x fp32 -> bf16 (RNE)
// ---------------------------------------------------------------------------
__global__ __launch_bounds__(256) void xconv(const float* __restrict__ x,
                                             unsigned short* __restrict__ xb) {
    const int stride = gridDim.x * 256;
    const int n8 = B_ * T_ * C_ / 8;
    for (int i = blockIdx.x * 256 + threadIdx.x; i < n8; i += stride) {
        f32x4 v0 = *(const f32x4*)(x + (size_t)i * 8);
        f32x4 v1 = *(const f32x4*)(x + (size_t)i * 8 + 4);
        short8 o;
#pragma unroll
        for (int e = 0; e < 4; ++e) {
            o[e] = (short)f2bf(v0[e]);
            o[e + 4] = (short)f2bf(v1[e]);
        }
        *(short8*)(xb + (size_t)i * 8) = o;
    }
}

// ---------------------------------------------------------------------------
// Kernel 1: W [K][N] fp32 -> Wt [mat][N][K] bf16
// ---------------------------------------------------------------------------
__global__ void wconv(const float* __restrict__ Wq, const float* __restrict__ Wk,
                      const float* __restrict__ Wv, unsigned short* __restrict__ Wt) {
    int idx = blockIdx.x * 256 + threadIdx.x;
    const int per = C_ * H_;
    if (idx >= 3 * per) return;
    int mat = idx / per;
    int rem = idx - mat * per;
    int n = rem / C_;
    int k = rem - n * C_;
    const float* W = (mat == 0) ? Wq : (mat == 1) ? Wk : Wv;
    Wt[idx] = f2bf(W[(size_t)k * H_ + n]);
}

// ---------------------------------------------------------------------------
// Kernel 2: QKV GEMM, tail-free. 1536 blocks x 256 thr (4 waves); block =
// 64 rows x 256 cols x ONE mat (bx>>9). Wave = 64r x 64c: each W-frag LDS
// read feeds 4 MFMAs. W chunk [256n][64k] single-buffered (32KB used, LDS
// padded to 48KB -> exactly 3 blocks/CU = 768 slots; 1536/768 = 2 exact
// generations, 12 waves/CU flat, zero tail). A prefetched one chunk ahead.
// ---------------------------------------------------------------------------
__global__ __launch_bounds__(256, 3) void qkv_gemm(
    const unsigned short* __restrict__ xb, const unsigned short* __restrict__ Wt,
    const float* __restrict__ bq, const float* __restrict__ bk,
    const float* __restrict__ bv,
    unsigned short* __restrict__ Qb, unsigned short* __restrict__ Kb,
    unsigned short* __restrict__ Vt)
{
    const int bx = blockIdx.x;                 // 0..1535
    const int mat = bx >> 9;
    const int rw = (bx & 511) * 64;
    const int tid = threadIdx.x;
    const int wid = tid >> 6;                  // 0..3 = wave col group
    const int lane = tid & 63;
    const int c16 = lane & 15;
    const int g = lane >> 4;

    __shared__ __align__(16) unsigned short Wl[256 * 64];   // 32KB used
    __shared__ char pad_[16384];                            // -> 48KB: 3 blocks/CU
    ((volatile char*)pad_)[tid] = 0;

    const char* wbB = (const char*)(Wt + (size_t)mat * H_ * C_);
    const unsigned short* xp[4];
#pragma unroll
    for (int rs = 0; rs < 4; ++rs)
        xp[rs] = xb + (size_t)(rw + rs * 16 + c16) * C_ + g * 8;

    f32x4 acc[4][4];
#pragma unroll
    for (int rs = 0; rs < 4; ++rs)
#pragma unroll
        for (int nt = 0; nt < 4; ++nt) acc[rs][nt] = f32x4{0.f, 0.f, 0.f, 0.f};

    // stage chunk ch (256 thr x 8 batches x 16B = 32KB), 16B-chunk XOR swizzle
#define STAGEW(ch)                                                              \
    {                                                                           \
        _Pragma("unroll")                                                       \
        for (int j = 0; j < 8; ++j) {                                           \
            int off = j * 4096 + wid * 1024 + lane * 16;                        \
            int row = off >> 7, colb = off & 127;                               \
            glds16(wbB + (size_t)row * 2048 + (ch) * 128 + (colb ^ ((row & 7) << 4)), \
                   (char*)&Wl[0] + j * 4096 + wid * 1024);                      \
        }                                                                       \
    }

    short8 xr[4][2];
#pragma unroll
    for (int rs = 0; rs < 4; ++rs) {
        xr[rs][0] = *(const short8*)(xp[rs]);
        xr[rs][1] = *(const short8*)(xp[rs] + 32);
    }

    for (int ch = 0; ch < 16; ++ch) {
        STAGEW(ch);
        __syncthreads();   // drains glds (W ready) after all waves done prior reads

        short8 af[4][2];
#pragma unroll
        for (int rs = 0; rs < 4; ++rs) {
            af[rs][0] = xr[rs][0];
            af[rs][1] = xr[rs][1];
        }
        if (ch < 15) {
#pragma unroll
            for (int rs = 0; rs < 4; ++rs) {
                xr[rs][0] = *(const short8*)(xp[rs] + (ch + 1) * 64);
                xr[rs][1] = *(const short8*)(xp[rs] + (ch + 1) * 64 + 32);
            }
        }

#pragma unroll
        for (int kk = 0; kk < 2; ++kk)
#pragma unroll
            for (int nt = 0; nt < 4; ++nt) {
                const int n = wid * 64 + nt * 16 + c16;
                short8 bfr = *(const short8*)((const char*)&Wl[0] + n * 128 +
                                              ((kk * 64 + g * 16) ^ ((n & 7) << 4)));
#pragma unroll
                for (int rs = 0; rs < 4; ++rs)
                    acc[rs][nt] = __builtin_amdgcn_mfma_f32_16x16x32_bf16(
                        af[rs][kk], bfr, acc[rs][nt], 0, 0, 0);
            }
        __syncthreads();   // all waves done reading Wl -> safe to restage
    }
#undef STAGEW

    const float* bias = (mat == 0) ? bq : (mat == 1) ? bk : bv;
#pragma unroll
    for (int rs = 0; rs < 4; ++rs)
#pragma unroll
        for (int nt = 0; nt < 4; ++nt) {
            const int n = wid * 64 + nt * 16 + c16;
            const float bias_v = bias[n];
#pragma unroll
            for (int rr = 0; rr < 4; ++rr) {
                const int rg = rw + rs * 16 + g * 4 + rr;
                const unsigned short hv = f2bf(acc[rs][nt][rr] + bias_v);
                if (mat == 0)      Qb[(size_t)rg * H_ + n] = hv;
                else if (mat == 1) Kb[(size_t)rg * H_ + n] = hv;
                else {
                    const int bb = rg >> 11, tt = rg & (T_ - 1);
                    Vt[((size_t)bb * H_ + n) * T_ + tt] = hv;
                }
            }
        }
}

// ---------------------------------------------------------------------------
// stage one KV tile, split across 4 waves (each stages 4KB of K + 4KB of V):
// K [32kv][256h] XOR-swz; V [256h][32kv] chunk-XOR-swz.
// ---------------------------------------------------------------------------
__device__ inline void stage_tile4(const char* kbB, const char* vtB, int sk,
                                   unsigned short* Kdst, unsigned short* Vdst,
                                   int wid, int lane) {
#pragma unroll
    for (int j = 0; j < 4; ++j) {
        int off = wid * 4096 + j * 1024 + lane * 16;
        int row = off >> 9, colb = off & 511;
        glds16(kbB + (size_t)(sk + row) * 512 + (colb ^ ((row & 7) << 4)),
               (char*)Kdst + off - lane * 16);
    }
#pragma unroll
    for (int j = 0; j < 4; ++j) {
        int off = wid * 4096 + j * 1024 + lane * 16;
        int h = off >> 6;                 // 64B per h-row
        int slot = lane & 3;
        int c = slot ^ ((h >> 1) & 3);    // logical kv-chunk at this slot
        glds16(vtB + (size_t)h * 4096 + (size_t)(sk + c * 8) * 2,
               (char*)Vdst + off - lane * 16);
    }
}

// ---------------------------------------------------------------------------
// Kernel 3: flash attention, kv-split with EXACT-LENGTH PAIRING (R16-proven).
// Block = 4 waves x 16 q = 64 q; every block runs exactly 33 kv-tiles.
// Grid 512 x 256 thr, dbuf K+V -> 2 blocks/CU = 8 waves/CU constant.
// ---------------------------------------------------------------------------
__global__ __launch_bounds__(256) void attn(
    const unsigned short* __restrict__ Qb, const unsigned short* __restrict__ Kb,
    const unsigned short* __restrict__ Vt, float* __restrict__ Opart,
    float2* __restrict__ ml)
{
    const int bx = blockIdx.x;                 // 0..511
    const int b = bx & 15;
    const int ab = (bx >> 4) & 1;              // 0 = A, 1 = B
    const int p = bx >> 5;                     // 0..15
    int qt[2], ts[2], te[2];
    if (ab == 0) {
        qt[0] = p;        ts[0] = 0;          te[0] = p + 1;
        qt[1] = 31 - p;   ts[1] = 32 - p;     te[1] = 64 - 2 * p;
    } else {
        qt[0] = 31 - p;   ts[0] = 0;          te[0] = 32 - p;
        qt[1] = p;        ts[1] = p + 1;      te[1] = 2 * p + 2;
    }
    const int tid = threadIdx.x;
    const int wid = tid >> 6;                  // 0..3
    const int lane = tid & 63;
    const int c16 = lane & 15;
    const int g = lane >> 4;
    const int hsw = (c16 >> 1) & 3;

    __shared__ __align__(16) unsigned short Kl[2][KVB * 256];   // 2 x 16KB
    __shared__ __align__(16) unsigned short Vl[2][256 * KVB];   // 2 x 16KB
    __shared__ __align__(16) unsigned short Pl[4][16 * 32];     // 4KB

    const char* kbB = (const char*)(Kb + (size_t)b * T_ * H_);
    const char* vtB = (const char*)(Vt + (size_t)b * H_ * T_);
    const float inv_scale = 0.022097086912079608f;   // 1/sqrt(2048)

#pragma unroll 1
    for (int ph = 0; ph < 2; ++ph) {
        const int qw = qt[ph] * 64 + wid * 16;
        const int qg = qw + c16;               // this lane's q row

        // Q fragments (B-operand of swapped QK^T)
        short8 qf[8];
        const unsigned short* qp = Qb + (size_t)(b * T_ + qg) * H_ + g * 8;
#pragma unroll
        for (int kc = 0; kc < 8; ++kc) qf[kc] = *(const short8*)(qp + kc * 32);

        f32x4 o[16];
#pragma unroll
        for (int i = 0; i < 16; ++i) o[i] = f32x4{0.f, 0.f, 0.f, 0.f};
        float m = -1e30f, ll = 0.f;

        stage_tile4(kbB, vtB, ts[ph] * KVB, &Kl[0][0], &Vl[0][0], wid, lane);
        __syncthreads();

        for (int t = ts[ph]; t < te[ph]; ++t) {
            const int cur = (t - ts[ph]) & 1;
            const int sk = t * KVB;

            if (t + 1 < te[ph])
                stage_tile4(kbB, vtB, sk + KVB, &Kl[cur ^ 1][0], &Vl[cur ^ 1][0],
                            wid, lane);

            if (sk <= qw + 15) {   // wave-uniform: skip fully-masked tiles
                // ---- S^T = K Q^T : lane holds S[q=qg][kv=sk+ct*16+g*4+rr] ----
                f32x4 sc[2];
                __builtin_amdgcn_s_setprio(1);
#pragma unroll
                for (int ct = 0; ct < 2; ++ct) {
                    f32x4 sa = f32x4{0.f, 0.f, 0.f, 0.f};
                    const int row = ct * 16 + c16;
#pragma unroll
                    for (int kc = 0; kc < 8; ++kc) {
                        short8 kf = *(const short8*)((const char*)&Kl[cur][0] + row * 512 +
                                                     ((kc * 64 + g * 16) ^ ((row & 7) << 4)));
                        sa = __builtin_amdgcn_mfma_f32_16x16x32_bf16(kf, qf[kc], sa, 0, 0, 0);
                    }
                    sc[ct] = sa;
                }
                __builtin_amdgcn_s_setprio(0);

                // ---- mask + scale ----
                float pv[8];
#pragma unroll
                for (int ct = 0; ct < 2; ++ct)
#pragma unroll
                    for (int rr = 0; rr < 4; ++rr) {
                        const int kv = sk + ct * 16 + g * 4 + rr;
                        float v = sc[ct][rr] * inv_scale;
                        pv[ct * 4 + rr] = (kv > qg) ? -1e30f : v;
                    }

                // ---- per-lane softmax (2 cross-lane ops) ----
                float pmax = fmaxf(fmaxf(fmaxf(pv[0], pv[1]), fmaxf(pv[2], pv[3])),
                                   fmaxf(fmaxf(pv[4], pv[5]), fmaxf(pv[6], pv[7])));
                pmax = fmaxf(pmax, __shfl_xor(pmax, 16, 64));
                pmax = fmaxf(pmax, __shfl_xor(pmax, 32, 64));
                if (!__all(pmax <= m + 8.f)) {       // T13 defer-max
                    const float nm = fmaxf(m, pmax);
                    const float scf = __expf(m - nm);
                    ll *= scf;
#pragma unroll
                    for (int mt = 0; mt < 16; ++mt) {
                        o[mt][0] *= scf; o[mt][1] *= scf;
                        o[mt][2] *= scf; o[mt][3] *= scf;
                    }
                    m = nm;
                }
                float rsum = 0.f;
#pragma unroll
                for (int i = 0; i < 8; ++i) { pv[i] = __expf(pv[i] - m); rsum += pv[i]; }
                rsum += __shfl_xor(rsum, 16, 64);
                rsum += __shfl_xor(rsum, 32, 64);
                ll += rsum;

                // ---- P -> bf16 -> wave-local swizzled LDS (4 b32 writes) ----
                unsigned int* pw = (unsigned int*)&Pl[wid][0];
#pragma unroll
                for (int ct = 0; ct < 2; ++ct)
#pragma unroll
                    for (int pr = 0; pr < 2; ++pr) {
                        int w = (ct * 8 + g * 2 + pr) ^ (hsw << 2);
                        unsigned int v = (unsigned int)f2bf(pv[ct * 4 + pr * 2]) |
                                         ((unsigned int)f2bf(pv[ct * 4 + pr * 2 + 1]) << 16);
                        pw[c16 * 16 + w] = v;
                    }
                asm volatile("s_waitcnt lgkmcnt(0)" ::: "memory");
                __builtin_amdgcn_sched_barrier(0);
                short8 pb = *(const short8*)((const char*)&Pl[wid][0] + c16 * 64 +
                                             ((g ^ hsw) << 4));

                // ---- O^T += V^T P^T ----
                __builtin_amdgcn_s_setprio(1);
#pragma unroll
                for (int mt = 0; mt < 16; ++mt) {
                    short8 vf = *(const short8*)((const char*)&Vl[cur][0] +
                                                 (mt * 16 + c16) * 64 + ((g ^ hsw) << 4));
                    o[mt] = __builtin_amdgcn_mfma_f32_16x16x32_bf16(vf, pb, o[mt], 0, 0, 0);
                }
                __builtin_amdgcn_s_setprio(0);
            }

            __syncthreads();   // drains (t+1) glds; guards dbuf + Pl reuse
        }

        // ---- epilogue: raw partials, slot = ph ----
        float* op = Opart + ((size_t)(ph * 16 + b) * T_ + qg) * H_;
#pragma unroll
        for (int mt = 0; mt < 16; ++mt)
            *(f32x4*)(op + mt * 16 + g * 4) = o[mt];
        if (g == 0)
            ml[(size_t)(ph * 16 + b) * T_ + qg] = make_float2(m, ll);
    }
}

// ---------------------------------------------------------------------------
// Kernel 4: combine the two kv-halves per q-row (flash merge).
// ---------------------------------------------------------------------------
__global__ __launch_bounds__(256) void combine(const float* __restrict__ Opart,
                                               const float2* __restrict__ ml,
                                               float* __restrict__ out) {
    const int stride = gridDim.x * 256;
    const int n4 = B_ * T_ * (H_ / 4);
    for (int u = blockIdx.x * 256 + threadIdx.x; u < n4; u += stride) {
        const int row = u >> 6;
        const int c4 = (u & 63) << 2;
        const float2 a = ml[row];
        const float2 bb = ml[B_ * T_ + row];
        const float mx = fmaxf(a.x, bb.x);
        const float w0 = __expf(a.x - mx);
        const float w1 = __expf(bb.x - mx);
        const float inv = 1.f / (a.y * w0 + bb.y * w1);
        f32x4 o0 = *(const f32x4*)(Opart + (size_t)row * H_ + c4);
        f32x4 o1 = *(const f32x4*)(Opart + (size_t)(B_ * T_) * H_ +
                                   (size_t)row * H_ + c4);
        f32x4 ov;
#pragma unroll
        for (int e = 0; e < 4; ++e) ov[e] = (o0[e] * w0 + o1[e] * w1) * inv;
        *(f32x4*)(out + (size_t)row * H_ + c4) = ov;
    }
}

// ---------------------------------------------------------------------------
extern "C" void kernel_launch(void* const* d_in, const int* in_sizes, int n_in,
                              void* d_out, int out_size, void* d_ws, size_t ws_size,
                              hipStream_t stream) {
    const float* x  = (const float*)d_in[0];
    const float* Wq = (const float*)d_in[1];
    const float* bq = (const float*)d_in[2];
    const float* Wk = (const float*)d_in[3];
    const float* bk = (const float*)d_in[4];
    const float* Wv = (const float*)d_in[5];
    const float* bv = (const float*)d_in[6];
    float* out = (float*)d_out;

    char* ws = (char*)d_ws;
    unsigned short* Wt = (unsigned short*)ws;                    // 1.5 MiB @0
    float2* ml         = (float2*)(ws + 1536u * 1024u);          // 512 KiB @1.5M
    unsigned short* Qb = (unsigned short*)(ws + (2u  << 20));    // 16 MiB
    unsigned short* Kb = (unsigned short*)(ws + (18u << 20));    // 16 MiB
    unsigned short* Vt = (unsigned short*)(ws + (34u << 20));    // 16 MiB
    unsigned short* xb = (unsigned short*)(ws + (50u << 20));    // 64 MiB
    float* Opart       = (float*)(ws + (50u << 20));             // reuses xb (dead after qkv)

    hipLaunchKernelGGL(xconv, dim3(2048), dim3(256), 0, stream, x, xb);
    hipLaunchKernelGGL(wconv, dim3((3 * C_ * H_ + 255) / 256), dim3(256), 0, stream,
                       Wq, Wk, Wv, Wt);
    hipLaunchKernelGGL(qkv_gemm, dim3(1536), dim3(256), 0, stream,
                       xb, Wt, bq, bk, bv, Qb, Kb, Vt);
    hipLaunchKernelGGL(attn, dim3(512), dim3(256), 0, stream,
                       Qb, Kb, Vt, Opart, ml);
    hipLaunchKernelGGL(combine, dim3(2048), dim3(256), 0, stream,
                       Opart, ml, out);
}

// Round 19
// 261.295 us; speedup vs baseline: 1.7676x; 1.0539x over previous
//
#include <hip/hip_runtime.h>
#include <hip/hip_bf16.h>
#include <cstdint>
#include <cstddef>

#define B_ 16
#define T_ 2048
#define C_ 1024
#define H_ 256
#define KVB 32

typedef __attribute__((ext_vector_type(8))) short short8;
typedef __attribute__((ext_vector_type(4))) float f32x4;

// fp32 -> bf16 (RNE)
__device__ inline unsigned short f2bf(float f) {
    unsigned int u = __builtin_bit_cast(unsigned int, f);
    unsigned int r = (u + 0x7FFFu + ((u >> 16) & 1u)) >> 16;
    return (unsigned short)r;
}

// async global->LDS, 16B/lane; LDS dest wave-uniform base (+lane*16 by HW)
__device__ inline void glds16(const void* g, void* l) {
    __builtin_amdgcn_global_load_lds(
        (const __attribute__((address_space(1))) unsigned int*)g,
        (__attribute__((address_space(3))) unsigned int*)l, 16, 0, 0);
}

// ---------------------------------------------------------------------------
// Kernel 0: x fp32 -> bf16 (RNE)
// ---------------------------------------------------------------------------
__global__ __launch_bounds__(256) void xconv(const float* __restrict__ x,
                                             unsigned short* __restrict__ xb) {
    const int stride = gridDim.x * 256;
    const int n8 = B_ * T_ * C_ / 8;
    for (int i = blockIdx.x * 256 + threadIdx.x; i < n8; i += stride) {
        f32x4 v0 = *(const f32x4*)(x + (size_t)i * 8);
        f32x4 v1 = *(const f32x4*)(x + (size_t)i * 8 + 4);
        short8 o;
#pragma unroll
        for (int e = 0; e < 4; ++e) {
            o[e] = (short)f2bf(v0[e]);
            o[e + 4] = (short)f2bf(v1[e]);
        }
        *(short8*)(xb + (size_t)i * 8) = o;
    }
}

// ---------------------------------------------------------------------------
// Kernel 1: W [K][N] fp32 -> Wt [mat][N][K] bf16
// ---------------------------------------------------------------------------
__global__ void wconv(const float* __restrict__ Wq, const float* __restrict__ Wk,
                      const float* __restrict__ Wv, unsigned short* __restrict__ Wt) {
    int idx = blockIdx.x * 256 + threadIdx.x;
    const int per = C_ * H_;
    if (idx >= 3 * per) return;
    int mat = idx / per;
    int rem = idx - mat * per;
    int n = rem / C_;
    int k = rem - n * C_;
    const float* W = (mat == 0) ? Wq : (mat == 1) ? Wk : Wv;
    Wt[idx] = f2bf(W[(size_t)k * H_ + n]);
}

// ---------------------------------------------------------------------------
// Kernel 2: QKV GEMM = R16 structure with K-chunk 32 (LDS 2x16KB -> 3
// blocks/CU = 768 slots; grid (256,3) = 768 blocks -> ONE generation, zero
// tail, 24 waves/CU flat). 8 waves = 2r x 2c... wave tile 32r x 128c; each
// W-frag LDS read feeds 2 MFMAs. W chunk [256n][32k] staged via swizzled
// glds16, DOUBLE-buffered (R16-proven pipeline). A prefetched 1 chunk ahead.
// ---------------------------------------------------------------------------
__global__ __launch_bounds__(512, 6) void qkv_gemm(
    const unsigned short* __restrict__ xb, const unsigned short* __restrict__ Wt,
    const float* __restrict__ bq, const float* __restrict__ bk,
    const float* __restrict__ bv,
    unsigned short* __restrict__ Qb, unsigned short* __restrict__ Kb,
    unsigned short* __restrict__ Vt)
{
    const int mat = blockIdx.y;
    const int tid = threadIdx.x;
    const int wid = tid >> 6;
    const int lane = tid & 63;
    const int c16 = lane & 15;
    const int g = lane >> 4;
    const int wr = wid >> 1, wc = wid & 1;
    const int rw = blockIdx.x * 128 + wr * 32;

    __shared__ __align__(16) unsigned short Wl[2][256 * 32];   // 2 x 16KB

    const char* wbB = (const char*)(Wt + (size_t)mat * H_ * C_);
    const unsigned short* xp0 = xb + (size_t)(rw + c16) * C_ + g * 8;
    const unsigned short* xp1 = xb + (size_t)(rw + 16 + c16) * C_ + g * 8;

    f32x4 acc[2][8];
#pragma unroll
    for (int rs = 0; rs < 2; ++rs)
#pragma unroll
        for (int nt = 0; nt < 8; ++nt) acc[rs][nt] = f32x4{0.f, 0.f, 0.f, 0.f};

    // stage chunk ch into Wl[buf]: [256n][32k] bf16 (64B rows), 16B-chunk XOR
#define STAGEW(ch, buf)                                                         \
    {                                                                           \
        _Pragma("unroll")                                                       \
        for (int j = 0; j < 2; ++j) {                                           \
            int off = j * 8192 + wid * 1024 + lane * 16;                        \
            int row = off >> 6, colb = off & 63;                                \
            glds16(wbB + (size_t)row * 2048 + (ch) * 64 + (colb ^ ((row & 3) << 4)), \
                   (char*)&Wl[buf][0] + j * 8192 + wid * 1024);                 \
        }                                                                       \
    }

    STAGEW(0, 0);
    short8 xr0 = *(const short8*)(xp0);
    short8 xr1 = *(const short8*)(xp1);
    __syncthreads();

    for (int ch = 0; ch < 32; ++ch) {
        const int cur = ch & 1;
        short8 af0 = xr0, af1 = xr1;
        if (ch < 31) {
            xr0 = *(const short8*)(xp0 + (ch + 1) * 32);
            xr1 = *(const short8*)(xp1 + (ch + 1) * 32);
            STAGEW(ch + 1, cur ^ 1);
        }
#pragma unroll
        for (int nt = 0; nt < 8; ++nt) {
            const int n = wc * 128 + nt * 16 + c16;
            short8 bfr = *(const short8*)((const char*)&Wl[cur][0] + n * 64 +
                                          ((g * 16) ^ ((n & 3) << 4)));
            acc[0][nt] = __builtin_amdgcn_mfma_f32_16x16x32_bf16(af0, bfr,
                                                                 acc[0][nt], 0, 0, 0);
            acc[1][nt] = __builtin_amdgcn_mfma_f32_16x16x32_bf16(af1, bfr,
                                                                 acc[1][nt], 0, 0, 0);
        }
        __syncthreads();   // drains glds(ch+1), guards dbuf swap
    }
#undef STAGEW

    const float* bias = (mat == 0) ? bq : (mat == 1) ? bk : bv;
#pragma unroll
    for (int rs = 0; rs < 2; ++rs)
#pragma unroll
        for (int nt = 0; nt < 8; ++nt) {
            const int n = wc * 128 + nt * 16 + c16;
            const float bias_v = bias[n];
#pragma unroll
            for (int rr = 0; rr < 4; ++rr) {
                const int rg = rw + rs * 16 + g * 4 + rr;
                const unsigned short hv = f2bf(acc[rs][nt][rr] + bias_v);
                if (mat == 0)      Qb[(size_t)rg * H_ + n] = hv;
                else if (mat == 1) Kb[(size_t)rg * H_ + n] = hv;
                else {
                    const int bb = rg >> 11, tt = rg & (T_ - 1);
                    Vt[((size_t)bb * H_ + n) * T_ + tt] = hv;
                }
            }
        }
}

// ---------------------------------------------------------------------------
// stage one KV tile, split across 4 waves (each stages 4KB of K + 4KB of V):
// K [32kv][256h] XOR-swz; V [256h][32kv] chunk-XOR-swz.
// ---------------------------------------------------------------------------
__device__ inline void stage_tile4(const char* kbB, const char* vtB, int sk,
                                   unsigned short* Kdst, unsigned short* Vdst,
                                   int wid, int lane) {
#pragma unroll
    for (int j = 0; j < 4; ++j) {
        int off = wid * 4096 + j * 1024 + lane * 16;
        int row = off >> 9, colb = off & 511;
        glds16(kbB + (size_t)(sk + row) * 512 + (colb ^ ((row & 7) << 4)),
               (char*)Kdst + off - lane * 16);
    }
#pragma unroll
    for (int j = 0; j < 4; ++j) {
        int off = wid * 4096 + j * 1024 + lane * 16;
        int h = off >> 6;                 // 64B per h-row
        int slot = lane & 3;
        int c = slot ^ ((h >> 1) & 3);    // logical kv-chunk at this slot
        glds16(vtB + (size_t)h * 4096 + (size_t)(sk + c * 8) * 2,
               (char*)Vdst + off - lane * 16);
    }
}

// ---------------------------------------------------------------------------
// Kernel 3: flash attention, kv-split with EXACT-LENGTH PAIRING (R16-proven).
// Block = 4 waves x 16 q = 64 q; every block runs exactly 33 kv-tiles.
// Grid 512 x 256 thr, dbuf K+V -> 2 blocks/CU = 8 waves/CU constant.
// ---------------------------------------------------------------------------
__global__ __launch_bounds__(256) void attn(
    const unsigned short* __restrict__ Qb, const unsigned short* __restrict__ Kb,
    const unsigned short* __restrict__ Vt, float* __restrict__ Opart,
    float2* __restrict__ ml)
{
    const int bx = blockIdx.x;                 // 0..511
    const int b = bx & 15;
    const int ab = (bx >> 4) & 1;              // 0 = A, 1 = B
    const int p = bx >> 5;                     // 0..15
    int qt[2], ts[2], te[2];
    if (ab == 0) {
        qt[0] = p;        ts[0] = 0;          te[0] = p + 1;
        qt[1] = 31 - p;   ts[1] = 32 - p;     te[1] = 64 - 2 * p;
    } else {
        qt[0] = 31 - p;   ts[0] = 0;          te[0] = 32 - p;
        qt[1] = p;        ts[1] = p + 1;      te[1] = 2 * p + 2;
    }
    const int tid = threadIdx.x;
    const int wid = tid >> 6;                  // 0..3
    const int lane = tid & 63;
    const int c16 = lane & 15;
    const int g = lane >> 4;
    const int hsw = (c16 >> 1) & 3;

    __shared__ __align__(16) unsigned short Kl[2][KVB * 256];   // 2 x 16KB
    __shared__ __align__(16) unsigned short Vl[2][256 * KVB];   // 2 x 16KB
    __shared__ __align__(16) unsigned short Pl[4][16 * 32];     // 4KB

    const char* kbB = (const char*)(Kb + (size_t)b * T_ * H_);
    const char* vtB = (const char*)(Vt + (size_t)b * H_ * T_);
    const float inv_scale = 0.022097086912079608f;   // 1/sqrt(2048)

#pragma unroll 1
    for (int ph = 0; ph < 2; ++ph) {
        const int qw = qt[ph] * 64 + wid * 16;
        const int qg = qw + c16;               // this lane's q row

        // Q fragments (B-operand of swapped QK^T)
        short8 qf[8];
        const unsigned short* qp = Qb + (size_t)(b * T_ + qg) * H_ + g * 8;
#pragma unroll
        for (int kc = 0; kc < 8; ++kc) qf[kc] = *(const short8*)(qp + kc * 32);

        f32x4 o[16];
#pragma unroll
        for (int i = 0; i < 16; ++i) o[i] = f32x4{0.f, 0.f, 0.f, 0.f};
        float m = -1e30f, ll = 0.f;

        stage_tile4(kbB, vtB, ts[ph] * KVB, &Kl[0][0], &Vl[0][0], wid, lane);
        __syncthreads();

        for (int t = ts[ph]; t < te[ph]; ++t) {
            const int cur = (t - ts[ph]) & 1;
            const int sk = t * KVB;

            if (t + 1 < te[ph])
                stage_tile4(kbB, vtB, sk + KVB, &Kl[cur ^ 1][0], &Vl[cur ^ 1][0],
                            wid, lane);

            if (sk <= qw + 15) {   // wave-uniform: skip fully-masked tiles
                // ---- S^T = K Q^T : lane holds S[q=qg][kv=sk+ct*16+g*4+rr] ----
                f32x4 sc[2];
                __builtin_amdgcn_s_setprio(1);
#pragma unroll
                for (int ct = 0; ct < 2; ++ct) {
                    f32x4 sa = f32x4{0.f, 0.f, 0.f, 0.f};
                    const int row = ct * 16 + c16;
#pragma unroll
                    for (int kc = 0; kc < 8; ++kc) {
                        short8 kf = *(const short8*)((const char*)&Kl[cur][0] + row * 512 +
                                                     ((kc * 64 + g * 16) ^ ((row & 7) << 4)));
                        sa = __builtin_amdgcn_mfma_f32_16x16x32_bf16(kf, qf[kc], sa, 0, 0, 0);
                    }
                    sc[ct] = sa;
                }
                __builtin_amdgcn_s_setprio(0);

                // ---- mask + scale ----
                float pv[8];
#pragma unroll
                for (int ct = 0; ct < 2; ++ct)
#pragma unroll
                    for (int rr = 0; rr < 4; ++rr) {
                        const int kv = sk + ct * 16 + g * 4 + rr;
                        float v = sc[ct][rr] * inv_scale;
                        pv[ct * 4 + rr] = (kv > qg) ? -1e30f : v;
                    }

                // ---- per-lane softmax (2 cross-lane ops) ----
                float pmax = fmaxf(fmaxf(fmaxf(pv[0], pv[1]), fmaxf(pv[2], pv[3])),
                                   fmaxf(fmaxf(pv[4], pv[5]), fmaxf(pv[6], pv[7])));
                pmax = fmaxf(pmax, __shfl_xor(pmax, 16, 64));
                pmax = fmaxf(pmax, __shfl_xor(pmax, 32, 64));
                if (!__all(pmax <= m + 8.f)) {       // T13 defer-max
                    const float nm = fmaxf(m, pmax);
                    const float scf = __expf(m - nm);
                    ll *= scf;
#pragma unroll
                    for (int mt = 0; mt < 16; ++mt) {
                        o[mt][0] *= scf; o[mt][1] *= scf;
                        o[mt][2] *= scf; o[mt][3] *= scf;
                    }
                    m = nm;
                }
                float rsum = 0.f;
#pragma unroll
                for (int i = 0; i < 8; ++i) { pv[i] = __expf(pv[i] - m); rsum += pv[i]; }
                rsum += __shfl_xor(rsum, 16, 64);
                rsum += __shfl_xor(rsum, 32, 64);
                ll += rsum;

                // ---- P -> bf16 -> wave-local swizzled LDS (4 b32 writes) ----
                unsigned int* pw = (unsigned int*)&Pl[wid][0];
#pragma unroll
                for (int ct = 0; ct < 2; ++ct)
#pragma unroll
                    for (int pr = 0; pr < 2; ++pr) {
                        int w = (ct * 8 + g * 2 + pr) ^ (hsw << 2);
                        unsigned int v = (unsigned int)f2bf(pv[ct * 4 + pr * 2]) |
                                         ((unsigned int)f2bf(pv[ct * 4 + pr * 2 + 1]) << 16);
                        pw[c16 * 16 + w] = v;
                    }
                asm volatile("s_waitcnt lgkmcnt(0)" ::: "memory");
                __builtin_amdgcn_sched_barrier(0);
                short8 pb = *(const short8*)((const char*)&Pl[wid][0] + c16 * 64 +
                                             ((g ^ hsw) << 4));

                // ---- O^T += V^T P^T ----
                __builtin_amdgcn_s_setprio(1);
#pragma unroll
                for (int mt = 0; mt < 16; ++mt) {
                    short8 vf = *(const short8*)((const char*)&Vl[cur][0] +
                                                 (mt * 16 + c16) * 64 + ((g ^ hsw) << 4));
                    o[mt] = __builtin_amdgcn_mfma_f32_16x16x32_bf16(vf, pb, o[mt], 0, 0, 0);
                }
                __builtin_amdgcn_s_setprio(0);
            }

            __syncthreads();   // drains (t+1) glds; guards dbuf + Pl reuse
        }

        // ---- epilogue: raw partials, slot = ph ----
        float* op = Opart + ((size_t)(ph * 16 + b) * T_ + qg) * H_;
#pragma unroll
        for (int mt = 0; mt < 16; ++mt)
            *(f32x4*)(op + mt * 16 + g * 4) = o[mt];
        if (g == 0)
            ml[(size_t)(ph * 16 + b) * T_ + qg] = make_float2(m, ll);
    }
}

// ---------------------------------------------------------------------------
// Kernel 4: combine the two kv-halves per q-row (flash merge).
// ---------------------------------------------------------------------------
__global__ __launch_bounds__(256) void combine(const float* __restrict__ Opart,
                                               const float2* __restrict__ ml,
                                               float* __restrict__ out) {
    const int stride = gridDim.x * 256;
    const int n4 = B_ * T_ * (H_ / 4);
    for (int u = blockIdx.x * 256 + threadIdx.x; u < n4; u += stride) {
        const int row = u >> 6;
        const int c4 = (u & 63) << 2;
        const float2 a = ml[row];
        const float2 bb = ml[B_ * T_ + row];
        const float mx = fmaxf(a.x, bb.x);
        const float w0 = __expf(a.x - mx);
        const float w1 = __expf(bb.x - mx);
        const float inv = 1.f / (a.y * w0 + bb.y * w1);
        f32x4 o0 = *(const f32x4*)(Opart + (size_t)row * H_ + c4);
        f32x4 o1 = *(const f32x4*)(Opart + (size_t)(B_ * T_) * H_ +
                                   (size_t)row * H_ + c4);
        f32x4 ov;
#pragma unroll
        for (int e = 0; e < 4; ++e) ov[e] = (o0[e] * w0 + o1[e] * w1) * inv;
        *(f32x4*)(out + (size_t)row * H_ + c4) = ov;
    }
}

// ---------------------------------------------------------------------------
extern "C" void kernel_launch(void* const* d_in, const int* in_sizes, int n_in,
                              void* d_out, int out_size, void* d_ws, size_t ws_size,
                              hipStream_t stream) {
    const float* x  = (const float*)d_in[0];
    const float* Wq = (const float*)d_in[1];
    const float* bq = (const float*)d_in[2];
    const float* Wk = (const float*)d_in[3];
    const float* bk = (const float*)d_in[4];
    const float* Wv = (const float*)d_in[5];
    const float* bv = (const float*)d_in[6];
    float* out = (float*)d_out;

    char* ws = (char*)d_ws;
    unsigned short* Wt = (unsigned short*)ws;                    // 1.5 MiB @0
    float2* ml         = (float2*)(ws + 1536u * 1024u);          // 512 KiB @1.5M
    unsigned short* Qb = (unsigned short*)(ws + (2u  << 20));    // 16 MiB
    unsigned short* Kb = (unsigned short*)(ws + (18u << 20));    // 16 MiB
    unsigned short* Vt = (unsigned short*)(ws + (34u << 20));    // 16 MiB
    unsigned short* xb = (unsigned short*)(ws + (50u << 20));    // 64 MiB
    float* Opart       = (float*)(ws + (50u << 20));             // reuses xb (dead after qkv)

    hipLaunchKernelGGL(xconv, dim3(2048), dim3(256), 0, stream, x, xb);
    hipLaunchKernelGGL(wconv, dim3((3 * C_ * H_ + 255) / 256), dim3(256), 0, stream,
                       Wq, Wk, Wv, Wt);
    hipLaunchKernelGGL(qkv_gemm, dim3(T_ * B_ / 128, 3), dim3(512), 0, stream,
                       xb, Wt, bq, bk, bv, Qb, Kb, Vt);
    hipLaunchKernelGGL(attn, dim3(512), dim3(256), 0, stream,
                       Qb, Kb, Vt, Opart, ml);
    hipLaunchKernelGGL(combine, dim3(2048), dim3(256), 0, stream,
                       Opart, ml, out);
}

// Round 20
// 254.326 us; speedup vs baseline: 1.8160x; 1.0274x over previous
//
#include <hip/hip_runtime.h>
#include <hip/hip_bf16.h>
#include <cstdint>
#include <cstddef>

#define B_ 16
#define T_ 2048
#define C_ 1024
#define H_ 256
#define KVB 32

typedef __attribute__((ext_vector_type(8))) short short8;
typedef __attribute__((ext_vector_type(4))) float f32x4;

// fp32 -> bf16 (RNE)
__device__ inline unsigned short f2bf(float f) {
    unsigned int u = __builtin_bit_cast(unsigned int, f);
    unsigned int r = (u + 0x7FFFu + ((u >> 16) & 1u)) >> 16;
    return (unsigned short)r;
}

// async global->LDS, 16B/lane; LDS dest wave-uniform base (+lane*16 by HW)
__device__ inline void glds16(const void* g, void* l) {
    __builtin_amdgcn_global_load_lds(
        (const __attribute__((address_space(1))) unsigned int*)g,
        (__attribute__((address_space(3))) unsigned int*)l, 16, 0, 0);
}

// ---------------------------------------------------------------------------
// Kernel 0: x fp32 -> bf16 (RNE)
// ---------------------------------------------------------------------------
__global__ __launch_bounds__(256) void xconv(const float* __restrict__ x,
                                             unsigned short* __restrict__ xb) {
    const int stride = gridDim.x * 256;
    const int n8 = B_ * T_ * C_ / 8;
    for (int i = blockIdx.x * 256 + threadIdx.x; i < n8; i += stride) {
        f32x4 v0 = *(const f32x4*)(x + (size_t)i * 8);
        f32x4 v1 = *(const f32x4*)(x + (size_t)i * 8 + 4);
        short8 o;
#pragma unroll
        for (int e = 0; e < 4; ++e) {
            o[e] = (short)f2bf(v0[e]);
            o[e + 4] = (short)f2bf(v1[e]);
        }
        *(short8*)(xb + (size_t)i * 8) = o;
    }
}

// ---------------------------------------------------------------------------
// Kernel 1: W [K][N] fp32 -> Wt [mat][N][K] bf16
// ---------------------------------------------------------------------------
__global__ void wconv(const float* __restrict__ Wq, const float* __restrict__ Wk,
                      const float* __restrict__ Wv, unsigned short* __restrict__ Wt) {
    int idx = blockIdx.x * 256 + threadIdx.x;
    const int per = C_ * H_;
    if (idx >= 3 * per) return;
    int mat = idx / per;
    int rem = idx - mat * per;
    int n = rem / C_;
    int k = rem - n * C_;
    const float* W = (mat == 0) ? Wq : (mat == 1) ? Wk : Wv;
    Wt[idx] = f2bf(W[(size_t)k * H_ + n]);
}

// ---------------------------------------------------------------------------
// Kernel 2: QKV GEMM = R16 pipeline, column-split for exact generations.
// Block = 512 thr (8 waves = 4r x 2c) over 128r x 128c; wave tile 32r x 64c.
// W chunk [128n][64k] (128B rows -> R16's proven swizzle), dbuf 2x16KB +
// 16KB pad = 48KB -> 3 blocks/CU = 768 slots; grid (512,3) = 1536 equal
// blocks = exactly 2 generations, zero tail. A prefetched 1 chunk ahead.
// ---------------------------------------------------------------------------
__global__ __launch_bounds__(512, 6) void qkv_gemm(
    const unsigned short* __restrict__ xb, const unsigned short* __restrict__ Wt,
    const float* __restrict__ bq, const float* __restrict__ bk,
    const float* __restrict__ bv,
    unsigned short* __restrict__ Qb, unsigned short* __restrict__ Kb,
    unsigned short* __restrict__ Vt)
{
    const int mat = blockIdx.y;
    const int bx = blockIdx.x;                 // 0..511
    const int rb = bx >> 1, cb = bx & 1;
    const int c0 = cb * 128;
    const int tid = threadIdx.x;
    const int wid = tid >> 6;
    const int lane = tid & 63;
    const int c16 = lane & 15;
    const int g = lane >> 4;
    const int wr = wid >> 1, wc = wid & 1;
    const int rw = rb * 128 + wr * 32;

    __shared__ __align__(16) unsigned short Wl[2][128 * 64];   // 2 x 16KB
    __shared__ char pad_[16384];                               // -> 48KB: 3 blk/CU
    ((volatile char*)pad_)[tid] = 0;

    const char* wbB = (const char*)(Wt + ((size_t)mat * H_ + c0) * C_);
    const unsigned short* xp0 = xb + (size_t)(rw + c16) * C_ + g * 8;
    const unsigned short* xp1 = xb + (size_t)(rw + 16 + c16) * C_ + g * 8;

    f32x4 acc[2][4];
#pragma unroll
    for (int rs = 0; rs < 2; ++rs)
#pragma unroll
        for (int nt = 0; nt < 4; ++nt) acc[rs][nt] = f32x4{0.f, 0.f, 0.f, 0.f};

    // stage chunk ch into Wl[buf]: [128n][64k] bf16 (128B rows), 16B-chunk XOR
#define STAGEW(ch, buf)                                                         \
    {                                                                           \
        _Pragma("unroll")                                                       \
        for (int j = 0; j < 2; ++j) {                                           \
            int off = j * 8192 + wid * 1024 + lane * 16;                        \
            int row = off >> 7, colb = off & 127;                               \
            glds16(wbB + (size_t)row * 2048 + (ch) * 128 + (colb ^ ((row & 7) << 4)), \
                   (char*)&Wl[buf][0] + j * 8192 + wid * 1024);                 \
        }                                                                       \
    }

    STAGEW(0, 0);
    short8 xr0[2], xr1[2];
    xr0[0] = *(const short8*)(xp0);       xr0[1] = *(const short8*)(xp0 + 32);
    xr1[0] = *(const short8*)(xp1);       xr1[1] = *(const short8*)(xp1 + 32);
    __syncthreads();

    for (int ch = 0; ch < 16; ++ch) {
        const int cur = ch & 1;
        short8 af0[2] = {xr0[0], xr0[1]};
        short8 af1[2] = {xr1[0], xr1[1]};
        if (ch < 15) {
            xr0[0] = *(const short8*)(xp0 + (ch + 1) * 64);
            xr0[1] = *(const short8*)(xp0 + (ch + 1) * 64 + 32);
            xr1[0] = *(const short8*)(xp1 + (ch + 1) * 64);
            xr1[1] = *(const short8*)(xp1 + (ch + 1) * 64 + 32);
            STAGEW(ch + 1, cur ^ 1);
        }
#pragma unroll
        for (int kk = 0; kk < 2; ++kk)
#pragma unroll
            for (int nt = 0; nt < 4; ++nt) {
                const int n = wc * 64 + nt * 16 + c16;      // local col 0..127
                short8 bfr = *(const short8*)((const char*)&Wl[cur][0] + n * 128 +
                                              ((kk * 64 + g * 16) ^ ((n & 7) << 4)));
                acc[0][nt] = __builtin_amdgcn_mfma_f32_16x16x32_bf16(af0[kk], bfr,
                                                                     acc[0][nt], 0, 0, 0);
                acc[1][nt] = __builtin_amdgcn_mfma_f32_16x16x32_bf16(af1[kk], bfr,
                                                                     acc[1][nt], 0, 0, 0);
            }
        __syncthreads();   // drains glds(ch+1), guards dbuf swap
    }
#undef STAGEW

    const float* bias = (mat == 0) ? bq : (mat == 1) ? bk : bv;
#pragma unroll
    for (int rs = 0; rs < 2; ++rs)
#pragma unroll
        for (int nt = 0; nt < 4; ++nt) {
            const int n = c0 + wc * 64 + nt * 16 + c16;
            const float bias_v = bias[n];
#pragma unroll
            for (int rr = 0; rr < 4; ++rr) {
                const int rg = rw + rs * 16 + g * 4 + rr;
                const unsigned short hv = f2bf(acc[rs][nt][rr] + bias_v);
                if (mat == 0)      Qb[(size_t)rg * H_ + n] = hv;
                else if (mat == 1) Kb[(size_t)rg * H_ + n] = hv;
                else {
                    const int bb = rg >> 11, tt = rg & (T_ - 1);
                    Vt[((size_t)bb * H_ + n) * T_ + tt] = hv;
                }
            }
        }
}

// ---------------------------------------------------------------------------
// stage one KV tile, split across 4 waves (each stages 4KB of K + 4KB of V):
// K [32kv][256h] XOR-swz; V [256h][32kv] chunk-XOR-swz.
// ---------------------------------------------------------------------------
__device__ inline void stage_tile4(const char* kbB, const char* vtB, int sk,
                                   unsigned short* Kdst, unsigned short* Vdst,
                                   int wid, int lane) {
#pragma unroll
    for (int j = 0; j < 4; ++j) {
        int off = wid * 4096 + j * 1024 + lane * 16;
        int row = off >> 9, colb = off & 511;
        glds16(kbB + (size_t)(sk + row) * 512 + (colb ^ ((row & 7) << 4)),
               (char*)Kdst + off - lane * 16);
    }
#pragma unroll
    for (int j = 0; j < 4; ++j) {
        int off = wid * 4096 + j * 1024 + lane * 16;
        int h = off >> 6;                 // 64B per h-row
        int slot = lane & 3;
        int c = slot ^ ((h >> 1) & 3);    // logical kv-chunk at this slot
        glds16(vtB + (size_t)h * 4096 + (size_t)(sk + c * 8) * 2,
               (char*)Vdst + off - lane * 16);
    }
}

// ---------------------------------------------------------------------------
// Kernel 3: flash attention, kv-split with EXACT-LENGTH PAIRING (R16-proven).
// Block = 4 waves x 16 q = 64 q; every block runs exactly 33 kv-tiles.
// Grid 512 x 256 thr, dbuf K+V -> 2 blocks/CU = 8 waves/CU constant.
// ---------------------------------------------------------------------------
__global__ __launch_bounds__(256) void attn(
    const unsigned short* __restrict__ Qb, const unsigned short* __restrict__ Kb,
    const unsigned short* __restrict__ Vt, float* __restrict__ Opart,
    float2* __restrict__ ml)
{
    const int bx = blockIdx.x;                 // 0..511
    const int b = bx & 15;
    const int ab = (bx >> 4) & 1;              // 0 = A, 1 = B
    const int p = bx >> 5;                     // 0..15
    int qt[2], ts[2], te[2];
    if (ab == 0) {
        qt[0] = p;        ts[0] = 0;          te[0] = p + 1;
        qt[1] = 31 - p;   ts[1] = 32 - p;     te[1] = 64 - 2 * p;
    } else {
        qt[0] = 31 - p;   ts[0] = 0;          te[0] = 32 - p;
        qt[1] = p;        ts[1] = p + 1;      te[1] = 2 * p + 2;
    }
    const int tid = threadIdx.x;
    const int wid = tid >> 6;                  // 0..3
    const int lane = tid & 63;
    const int c16 = lane & 15;
    const int g = lane >> 4;
    const int hsw = (c16 >> 1) & 3;

    __shared__ __align__(16) unsigned short Kl[2][KVB * 256];   // 2 x 16KB
    __shared__ __align__(16) unsigned short Vl[2][256 * KVB];   // 2 x 16KB
    __shared__ __align__(16) unsigned short Pl[4][16 * 32];     // 4KB

    const char* kbB = (const char*)(Kb + (size_t)b * T_ * H_);
    const char* vtB = (const char*)(Vt + (size_t)b * H_ * T_);
    const float inv_scale = 0.022097086912079608f;   // 1/sqrt(2048)

#pragma unroll 1
    for (int ph = 0; ph < 2; ++ph) {
        const int qw = qt[ph] * 64 + wid * 16;
        const int qg = qw + c16;               // this lane's q row

        // Q fragments (B-operand of swapped QK^T)
        short8 qf[8];
        const unsigned short* qp = Qb + (size_t)(b * T_ + qg) * H_ + g * 8;
#pragma unroll
        for (int kc = 0; kc < 8; ++kc) qf[kc] = *(const short8*)(qp + kc * 32);

        f32x4 o[16];
#pragma unroll
        for (int i = 0; i < 16; ++i) o[i] = f32x4{0.f, 0.f, 0.f, 0.f};
        float m = -1e30f, ll = 0.f;

        stage_tile4(kbB, vtB, ts[ph] * KVB, &Kl[0][0], &Vl[0][0], wid, lane);
        __syncthreads();

        for (int t = ts[ph]; t < te[ph]; ++t) {
            const int cur = (t - ts[ph]) & 1;
            const int sk = t * KVB;

            if (t + 1 < te[ph])
                stage_tile4(kbB, vtB, sk + KVB, &Kl[cur ^ 1][0], &Vl[cur ^ 1][0],
                            wid, lane);

            if (sk <= qw + 15) {   // wave-uniform: skip fully-masked tiles
                // ---- S^T = K Q^T : lane holds S[q=qg][kv=sk+ct*16+g*4+rr] ----
                f32x4 sc[2];
                __builtin_amdgcn_s_setprio(1);
#pragma unroll
                for (int ct = 0; ct < 2; ++ct) {
                    f32x4 sa = f32x4{0.f, 0.f, 0.f, 0.f};
                    const int row = ct * 16 + c16;
#pragma unroll
                    for (int kc = 0; kc < 8; ++kc) {
                        short8 kf = *(const short8*)((const char*)&Kl[cur][0] + row * 512 +
                                                     ((kc * 64 + g * 16) ^ ((row & 7) << 4)));
                        sa = __builtin_amdgcn_mfma_f32_16x16x32_bf16(kf, qf[kc], sa, 0, 0, 0);
                    }
                    sc[ct] = sa;
                }
                __builtin_amdgcn_s_setprio(0);

                // ---- mask + scale ----
                float pv[8];
#pragma unroll
                for (int ct = 0; ct < 2; ++ct)
#pragma unroll
                    for (int rr = 0; rr < 4; ++rr) {
                        const int kv = sk + ct * 16 + g * 4 + rr;
                        float v = sc[ct][rr] * inv_scale;
                        pv[ct * 4 + rr] = (kv > qg) ? -1e30f : v;
                    }

                // ---- per-lane softmax (2 cross-lane ops) ----
                float pmax = fmaxf(fmaxf(fmaxf(pv[0], pv[1]), fmaxf(pv[2], pv[3])),
                                   fmaxf(fmaxf(pv[4], pv[5]), fmaxf(pv[6], pv[7])));
                pmax = fmaxf(pmax, __shfl_xor(pmax, 16, 64));
                pmax = fmaxf(pmax, __shfl_xor(pmax, 32, 64));
                if (!__all(pmax <= m + 8.f)) {       // T13 defer-max
                    const float nm = fmaxf(m, pmax);
                    const float scf = __expf(m - nm);
                    ll *= scf;
#pragma unroll
                    for (int mt = 0; mt < 16; ++mt) {
                        o[mt][0] *= scf; o[mt][1] *= scf;
                        o[mt][2] *= scf; o[mt][3] *= scf;
                    }
                    m = nm;
                }
                float rsum = 0.f;
#pragma unroll
                for (int i = 0; i < 8; ++i) { pv[i] = __expf(pv[i] - m); rsum += pv[i]; }
                rsum += __shfl_xor(rsum, 16, 64);
                rsum += __shfl_xor(rsum, 32, 64);
                ll += rsum;

                // ---- P -> bf16 -> wave-local swizzled LDS (4 b32 writes) ----
                unsigned int* pw = (unsigned int*)&Pl[wid][0];
#pragma unroll
                for (int ct = 0; ct < 2; ++ct)
#pragma unroll
                    for (int pr = 0; pr < 2; ++pr) {
                        int w = (ct * 8 + g * 2 + pr) ^ (hsw << 2);
                        unsigned int v = (unsigned int)f2bf(pv[ct * 4 + pr * 2]) |
                                         ((unsigned int)f2bf(pv[ct * 4 + pr * 2 + 1]) << 16);
                        pw[c16 * 16 + w] = v;
                    }
                asm volatile("s_waitcnt lgkmcnt(0)" ::: "memory");
                __builtin_amdgcn_sched_barrier(0);
                short8 pb = *(const short8*)((const char*)&Pl[wid][0] + c16 * 64 +
                                             ((g ^ hsw) << 4));

                // ---- O^T += V^T P^T ----
                __builtin_amdgcn_s_setprio(1);
#pragma unroll
                for (int mt = 0; mt < 16; ++mt) {
                    short8 vf = *(const short8*)((const char*)&Vl[cur][0] +
                                                 (mt * 16 + c16) * 64 + ((g ^ hsw) << 4));
                    o[mt] = __builtin_amdgcn_mfma_f32_16x16x32_bf16(vf, pb, o[mt], 0, 0, 0);
                }
                __builtin_amdgcn_s_setprio(0);
            }

            __syncthreads();   // drains (t+1) glds; guards dbuf + Pl reuse
        }

        // ---- epilogue: raw partials, slot = ph ----
        float* op = Opart + ((size_t)(ph * 16 + b) * T_ + qg) * H_;
#pragma unroll
        for (int mt = 0; mt < 16; ++mt)
            *(f32x4*)(op + mt * 16 + g * 4) = o[mt];
        if (g == 0)
            ml[(size_t)(ph * 16 + b) * T_ + qg] = make_float2(m, ll);
    }
}

// ---------------------------------------------------------------------------
// Kernel 4: combine the two kv-halves per q-row (flash merge).
// ---------------------------------------------------------------------------
__global__ __launch_bounds__(256) void combine(const float* __restrict__ Opart,
                                               const float2* __restrict__ ml,
                                               float* __restrict__ out) {
    const int stride = gridDim.x * 256;
    const int n4 = B_ * T_ * (H_ / 4);
    for (int u = blockIdx.x * 256 + threadIdx.x; u < n4; u += stride) {
        const int row = u >> 6;
        const int c4 = (u & 63) << 2;
        const float2 a = ml[row];
        const float2 bb = ml[B_ * T_ + row];
        const float mx = fmaxf(a.x, bb.x);
        const float w0 = __expf(a.x - mx);
        const float w1 = __expf(bb.x - mx);
        const float inv = 1.f / (a.y * w0 + bb.y * w1);
        f32x4 o0 = *(const f32x4*)(Opart + (size_t)row * H_ + c4);
        f32x4 o1 = *(const f32x4*)(Opart + (size_t)(B_ * T_) * H_ +
                                   (size_t)row * H_ + c4);
        f32x4 ov;
#pragma unroll
        for (int e = 0; e < 4; ++e) ov[e] = (o0[e] * w0 + o1[e] * w1) * inv;
        *(f32x4*)(out + (size_t)row * H_ + c4) = ov;
    }
}

// ---------------------------------------------------------------------------
extern "C" void kernel_launch(void* const* d_in, const int* in_sizes, int n_in,
                              void* d_out, int out_size, void* d_ws, size_t ws_size,
                              hipStream_t stream) {
    const float* x  = (const float*)d_in[0];
    const float* Wq = (const float*)d_in[1];
    const float* bq = (const float*)d_in[2];
    const float* Wk = (const float*)d_in[3];
    const float* bk = (const float*)d_in[4];
    const float* Wv = (const float*)d_in[5];
    const float* bv = (const float*)d_in[6];
    float* out = (float*)d_out;

    char* ws = (char*)d_ws;
    unsigned short* Wt = (unsigned short*)ws;                    // 1.5 MiB @0
    float2* ml         = (float2*)(ws + 1536u * 1024u);          // 512 KiB @1.5M
    unsigned short* Qb = (unsigned short*)(ws + (2u  << 20));    // 16 MiB
    unsigned short* Kb = (unsigned short*)(ws + (18u << 20));    // 16 MiB
    unsigned short* Vt = (unsigned short*)(ws + (34u << 20));    // 16 MiB
    unsigned short* xb = (unsigned short*)(ws + (50u << 20));    // 64 MiB
    float* Opart       = (float*)(ws + (50u << 20));             // reuses xb (dead after qkv)

    hipLaunchKernelGGL(xconv, dim3(2048), dim3(256), 0, stream, x, xb);
    hipLaunchKernelGGL(wconv, dim3((3 * C_ * H_ + 255) / 256), dim3(256), 0, stream,
                       Wq, Wk, Wv, Wt);
    hipLaunchKernelGGL(qkv_gemm, dim3(512, 3), dim3(512), 0, stream,
                       xb, Wt, bq, bk, bv, Qb, Kb, Vt);
    hipLaunchKernelGGL(attn, dim3(512), dim3(256), 0, stream,
                       Qb, Kb, Vt, Opart, ml);
    hipLaunchKernelGGL(combine, dim3(2048), dim3(256), 0, stream,
                       Opart, ml, out);
}

// Round 21
// 223.316 us; speedup vs baseline: 2.0682x; 1.1389x over previous
//
#include <hip/hip_runtime.h>
#include <hip/hip_bf16.h>
#include <cstdint>
#include <cstddef>

#define B_ 16
#define T_ 2048
#define C_ 1024
#define H_ 256
#define KVB 32

typedef __attribute__((ext_vector_type(8))) short short8;
typedef __attribute__((ext_vector_type(4))) float f32x4;

// fp32 -> bf16 (RNE)
__device__ inline unsigned short f2bf(float f) {
    unsigned int u = __builtin_bit_cast(unsigned int, f);
    unsigned int r = (u + 0x7FFFu + ((u >> 16) & 1u)) >> 16;
    return (unsigned short)r;
}

// async global->LDS, 16B/lane; LDS dest wave-uniform base (+lane*16 by HW)
__device__ inline void glds16(const void* g, void* l) {
    __builtin_amdgcn_global_load_lds(
        (const __attribute__((address_space(1))) unsigned int*)g,
        (__attribute__((address_space(3))) unsigned int*)l, 16, 0, 0);
}

// ---------------------------------------------------------------------------
// Kernel 0: x fp32 -> bf16 (RNE)
// ---------------------------------------------------------------------------
__global__ __launch_bounds__(256) void xconv(const float* __restrict__ x,
                                             unsigned short* __restrict__ xb) {
    const int stride = gridDim.x * 256;
    const int n8 = B_ * T_ * C_ / 8;
    for (int i = blockIdx.x * 256 + threadIdx.x; i < n8; i += stride) {
        f32x4 v0 = *(const f32x4*)(x + (size_t)i * 8);
        f32x4 v1 = *(const f32x4*)(x + (size_t)i * 8 + 4);
        short8 o;
#pragma unroll
        for (int e = 0; e < 4; ++e) {
            o[e] = (short)f2bf(v0[e]);
            o[e + 4] = (short)f2bf(v1[e]);
        }
        *(short8*)(xb + (size_t)i * 8) = o;
    }
}

// ---------------------------------------------------------------------------
// Kernel 1: W [K][N] fp32 -> Wt [mat][N][K] bf16
// ---------------------------------------------------------------------------
__global__ void wconv(const float* __restrict__ Wq, const float* __restrict__ Wk,
                      const float* __restrict__ Wv, unsigned short* __restrict__ Wt) {
    int idx = blockIdx.x * 256 + threadIdx.x;
    const int per = C_ * H_;
    if (idx >= 3 * per) return;
    int mat = idx / per;
    int rem = idx - mat * per;
    int n = rem / C_;
    int k = rem - n * C_;
    const float* W = (mat == 0) ? Wq : (mat == 1) ? Wk : Wv;
    Wt[idx] = f2bf(W[(size_t)k * H_ + n]);
}

// ---------------------------------------------------------------------------
// Kernel 2: QKV GEMM (R16-proven, best measured: 96 us). Block = 512 thr
// (8 waves = 4r x 2c) over 128r x 256c; wave tile 32r x 128c (each W-frag
// LDS read feeds 2 MFMAs). W chunk [256n][64k] staged via swizzled glds16,
// DOUBLE-buffered (2 x 32KB LDS). A (xb bf16) register-prefetched 1 chunk
// ahead. Grid (256, 3).
// ---------------------------------------------------------------------------
__global__ __launch_bounds__(512, 4) void qkv_gemm(
    const unsigned short* __restrict__ xb, const unsigned short* __restrict__ Wt,
    const float* __restrict__ bq, const float* __restrict__ bk,
    const float* __restrict__ bv,
    unsigned short* __restrict__ Qb, unsigned short* __restrict__ Kb,
    unsigned short* __restrict__ Vt)
{
    const int mat = blockIdx.y;
    const int tid = threadIdx.x;
    const int wid = tid >> 6;
    const int lane = tid & 63;
    const int c16 = lane & 15;
    const int g = lane >> 4;
    const int wr = wid >> 1, wc = wid & 1;
    const int rw = blockIdx.x * 128 + wr * 32;

    __shared__ __align__(16) unsigned short Wl[2][256 * 64];   // 2 x 32KB

    const char* wbB = (const char*)(Wt + (size_t)mat * H_ * C_);
    const unsigned short* xp0 = xb + (size_t)(rw + c16) * C_ + g * 8;
    const unsigned short* xp1 = xb + (size_t)(rw + 16 + c16) * C_ + g * 8;

    f32x4 acc[2][8];
#pragma unroll
    for (int rs = 0; rs < 2; ++rs)
#pragma unroll
        for (int nt = 0; nt < 8; ++nt) acc[rs][nt] = f32x4{0.f, 0.f, 0.f, 0.f};

#pragma unroll
    for (int j = 0; j < 4; ++j) {
        int off = j * 8192 + wid * 1024 + lane * 16;
        int row = off >> 7, colb = off & 127;
        glds16(wbB + (size_t)row * 2048 + (colb ^ ((row & 7) << 4)),
               (char*)&Wl[0][0] + j * 8192 + wid * 1024);
    }
    short8 xr0[2], xr1[2];
    xr0[0] = *(const short8*)(xp0);       xr0[1] = *(const short8*)(xp0 + 32);
    xr1[0] = *(const short8*)(xp1);       xr1[1] = *(const short8*)(xp1 + 32);
    __syncthreads();

    for (int ch = 0; ch < 16; ++ch) {
        const int cur = ch & 1;
        short8 af0[2] = {xr0[0], xr0[1]};
        short8 af1[2] = {xr1[0], xr1[1]};
        if (ch < 15) {
            xr0[0] = *(const short8*)(xp0 + (ch + 1) * 64);
            xr0[1] = *(const short8*)(xp0 + (ch + 1) * 64 + 32);
            xr1[0] = *(const short8*)(xp1 + (ch + 1) * 64);
            xr1[1] = *(const short8*)(xp1 + (ch + 1) * 64 + 32);
#pragma unroll
            for (int j = 0; j < 4; ++j) {
                int off = j * 8192 + wid * 1024 + lane * 16;
                int row = off >> 7, colb = off & 127;
                glds16(wbB + (size_t)row * 2048 + (ch + 1) * 128 + (colb ^ ((row & 7) << 4)),
                       (char*)&Wl[cur ^ 1][0] + j * 8192 + wid * 1024);
            }
        }
#pragma unroll
        for (int kk = 0; kk < 2; ++kk)
#pragma unroll
            for (int nt = 0; nt < 8; ++nt) {
                const int n = wc * 128 + nt * 16 + c16;
                short8 bfr = *(const short8*)((const char*)&Wl[cur][0] + n * 128 +
                                              ((kk * 64 + g * 16) ^ ((n & 7) << 4)));
                acc[0][nt] = __builtin_amdgcn_mfma_f32_16x16x32_bf16(af0[kk], bfr,
                                                                     acc[0][nt], 0, 0, 0);
                acc[1][nt] = __builtin_amdgcn_mfma_f32_16x16x32_bf16(af1[kk], bfr,
                                                                     acc[1][nt], 0, 0, 0);
            }
        __syncthreads();   // drains glds(ch+1), guards dbuf swap
    }

    const float* bias = (mat == 0) ? bq : (mat == 1) ? bk : bv;
#pragma unroll
    for (int rs = 0; rs < 2; ++rs)
#pragma unroll
        for (int nt = 0; nt < 8; ++nt) {
            const int n = wc * 128 + nt * 16 + c16;
            const float bias_v = bias[n];
#pragma unroll
            for (int rr = 0; rr < 4; ++rr) {
                const int rg = rw + rs * 16 + g * 4 + rr;
                const unsigned short hv = f2bf(acc[rs][nt][rr] + bias_v);
                if (mat == 0)      Qb[(size_t)rg * H_ + n] = hv;
                else if (mat == 1) Kb[(size_t)rg * H_ + n] = hv;
                else {
                    const int bb = rg >> 11, tt = rg & (T_ - 1);
                    Vt[((size_t)bb * H_ + n) * T_ + tt] = hv;
                }
            }
        }
}

// ---------------------------------------------------------------------------
// stage one KV tile, split across 4 waves (each stages 4KB of K + 4KB of V):
// K [32kv][256h] XOR-swz; V [256h][32kv] chunk-XOR-swz.
// ---------------------------------------------------------------------------
__device__ inline void stage_tile4(const char* kbB, const char* vtB, int sk,
                                   unsigned short* Kdst, unsigned short* Vdst,
                                   int wid, int lane) {
#pragma unroll
    for (int j = 0; j < 4; ++j) {
        int off = wid * 4096 + j * 1024 + lane * 16;
        int row = off >> 9, colb = off & 511;
        glds16(kbB + (size_t)(sk + row) * 512 + (colb ^ ((row & 7) << 4)),
               (char*)Kdst + off - lane * 16);
    }
#pragma unroll
    for (int j = 0; j < 4; ++j) {
        int off = wid * 4096 + j * 1024 + lane * 16;
        int h = off >> 6;                 // 64B per h-row
        int slot = lane & 3;
        int c = slot ^ ((h >> 1) & 3);    // logical kv-chunk at this slot
        glds16(vtB + (size_t)h * 4096 + (size_t)(sk + c * 8) * 2,
               (char*)Vdst + off - lane * 16);
    }
}

// ---------------------------------------------------------------------------
// Kernel 3: flash attention, kv-split with EXACT-LENGTH PAIRING (R16-proven).
// Block = 4 waves x 16 q = 64 q. Every block runs exactly 33 kv-tiles:
//   A(p): [first half of q-tile p] + [second half of q-tile 31-p]
//   B(p): [first half of q-tile 31-p] + [second half of q-tile p]
// Grid 512 x 256 thr, dbuf K+V (68.8KB LDS) -> 2 blocks/CU = 8 waves/CU,
// constant for the whole kernel (zero tail, zero stragglers).
// ---------------------------------------------------------------------------
__global__ __launch_bounds__(256) void attn(
    const unsigned short* __restrict__ Qb, const unsigned short* __restrict__ Kb,
    const unsigned short* __restrict__ Vt, float* __restrict__ Opart,
    float2* __restrict__ ml)
{
    const int bx = blockIdx.x;                 // 0..511
    const int b = bx & 15;
    const int ab = (bx >> 4) & 1;              // 0 = A, 1 = B
    const int p = bx >> 5;                     // 0..15
    int qt[2], ts[2], te[2];
    if (ab == 0) {
        qt[0] = p;        ts[0] = 0;          te[0] = p + 1;
        qt[1] = 31 - p;   ts[1] = 32 - p;     te[1] = 64 - 2 * p;
    } else {
        qt[0] = 31 - p;   ts[0] = 0;          te[0] = 32 - p;
        qt[1] = p;        ts[1] = p + 1;      te[1] = 2 * p + 2;
    }
    const int tid = threadIdx.x;
    const int wid = tid >> 6;                  // 0..3
    const int lane = tid & 63;
    const int c16 = lane & 15;
    const int g = lane >> 4;
    const int hsw = (c16 >> 1) & 3;

    __shared__ __align__(16) unsigned short Kl[2][KVB * 256];   // 2 x 16KB
    __shared__ __align__(16) unsigned short Vl[2][256 * KVB];   // 2 x 16KB
    __shared__ __align__(16) unsigned short Pl[4][16 * 32];     // 4KB

    const char* kbB = (const char*)(Kb + (size_t)b * T_ * H_);
    const char* vtB = (const char*)(Vt + (size_t)b * H_ * T_);
    const float inv_scale = 0.022097086912079608f;   // 1/sqrt(2048)

#pragma unroll 1
    for (int ph = 0; ph < 2; ++ph) {
        const int qw = qt[ph] * 64 + wid * 16;
        const int qg = qw + c16;               // this lane's q row

        // Q fragments (B-operand of swapped QK^T)
        short8 qf[8];
        const unsigned short* qp = Qb + (size_t)(b * T_ + qg) * H_ + g * 8;
#pragma unroll
        for (int kc = 0; kc < 8; ++kc) qf[kc] = *(const short8*)(qp + kc * 32);

        f32x4 o[16];
#pragma unroll
        for (int i = 0; i < 16; ++i) o[i] = f32x4{0.f, 0.f, 0.f, 0.f};
        float m = -1e30f, ll = 0.f;

        stage_tile4(kbB, vtB, ts[ph] * KVB, &Kl[0][0], &Vl[0][0], wid, lane);
        __syncthreads();

        for (int t = ts[ph]; t < te[ph]; ++t) {
            const int cur = (t - ts[ph]) & 1;
            const int sk = t * KVB;

            if (t + 1 < te[ph])
                stage_tile4(kbB, vtB, sk + KVB, &Kl[cur ^ 1][0], &Vl[cur ^ 1][0],
                            wid, lane);

            if (sk <= qw + 15) {   // wave-uniform: skip fully-masked tiles
                // ---- S^T = K Q^T : lane holds S[q=qg][kv=sk+ct*16+g*4+rr] ----
                f32x4 sc[2];
                __builtin_amdgcn_s_setprio(1);
#pragma unroll
                for (int ct = 0; ct < 2; ++ct) {
                    f32x4 sa = f32x4{0.f, 0.f, 0.f, 0.f};
                    const int row = ct * 16 + c16;
#pragma unroll
                    for (int kc = 0; kc < 8; ++kc) {
                        short8 kf = *(const short8*)((const char*)&Kl[cur][0] + row * 512 +
                                                     ((kc * 64 + g * 16) ^ ((row & 7) << 4)));
                        sa = __builtin_amdgcn_mfma_f32_16x16x32_bf16(kf, qf[kc], sa, 0, 0, 0);
                    }
                    sc[ct] = sa;
                }
                __builtin_amdgcn_s_setprio(0);

                // ---- mask + scale ----
                float pv[8];
#pragma unroll
                for (int ct = 0; ct < 2; ++ct)
#pragma unroll
                    for (int rr = 0; rr < 4; ++rr) {
                        const int kv = sk + ct * 16 + g * 4 + rr;
                        float v = sc[ct][rr] * inv_scale;
                        pv[ct * 4 + rr] = (kv > qg) ? -1e30f : v;
                    }

                // ---- per-lane softmax (2 cross-lane ops) ----
                float pmax = fmaxf(fmaxf(fmaxf(pv[0], pv[1]), fmaxf(pv[2], pv[3])),
                                   fmaxf(fmaxf(pv[4], pv[5]), fmaxf(pv[6], pv[7])));
                pmax = fmaxf(pmax, __shfl_xor(pmax, 16, 64));
                pmax = fmaxf(pmax, __shfl_xor(pmax, 32, 64));
                if (!__all(pmax <= m + 8.f)) {       // T13 defer-max
                    const float nm = fmaxf(m, pmax);
                    const float scf = __expf(m - nm);
                    ll *= scf;
#pragma unroll
                    for (int mt = 0; mt < 16; ++mt) {
                        o[mt][0] *= scf; o[mt][1] *= scf;
                        o[mt][2] *= scf; o[mt][3] *= scf;
                    }
                    m = nm;
                }
                float rsum = 0.f;
#pragma unroll
                for (int i = 0; i < 8; ++i) { pv[i] = __expf(pv[i] - m); rsum += pv[i]; }
                rsum += __shfl_xor(rsum, 16, 64);
                rsum += __shfl_xor(rsum, 32, 64);
                ll += rsum;

                // ---- P -> bf16 -> wave-local swizzled LDS (4 b32 writes) ----
                unsigned int* pw = (unsigned int*)&Pl[wid][0];
#pragma unroll
                for (int ct = 0; ct < 2; ++ct)
#pragma unroll
                    for (int pr = 0; pr < 2; ++pr) {
                        int w = (ct * 8 + g * 2 + pr) ^ (hsw << 2);
                        unsigned int v = (unsigned int)f2bf(pv[ct * 4 + pr * 2]) |
                                         ((unsigned int)f2bf(pv[ct * 4 + pr * 2 + 1]) << 16);
                        pw[c16 * 16 + w] = v;
                    }
                asm volatile("s_waitcnt lgkmcnt(0)" ::: "memory");
                __builtin_amdgcn_sched_barrier(0);
                short8 pb = *(const short8*)((const char*)&Pl[wid][0] + c16 * 64 +
                                             ((g ^ hsw) << 4));

                // ---- O^T += V^T P^T ----
                __builtin_amdgcn_s_setprio(1);
#pragma unroll
                for (int mt = 0; mt < 16; ++mt) {
                    short8 vf = *(const short8*)((const char*)&Vl[cur][0] +
                                                 (mt * 16 + c16) * 64 + ((g ^ hsw) << 4));
                    o[mt] = __builtin_amdgcn_mfma_f32_16x16x32_bf16(vf, pb, o[mt], 0, 0, 0);
                }
                __builtin_amdgcn_s_setprio(0);
            }

            __syncthreads();   // drains (t+1) glds; guards dbuf + Pl reuse
        }

        // ---- epilogue: raw partials, slot = ph ----
        float* op = Opart + ((size_t)(ph * 16 + b) * T_ + qg) * H_;
#pragma unroll
        for (int mt = 0; mt < 16; ++mt)
            *(f32x4*)(op + mt * 16 + g * 4) = o[mt];
        if (g == 0)
            ml[(size_t)(ph * 16 + b) * T_ + qg] = make_float2(m, ll);
    }
}

// ---------------------------------------------------------------------------
// Kernel 4: combine the two kv-halves per q-row (flash merge).
// ---------------------------------------------------------------------------
__global__ __launch_bounds__(256) void combine(const float* __restrict__ Opart,
                                               const float2* __restrict__ ml,
                                               float* __restrict__ out) {
    const int stride = gridDim.x * 256;
    const int n4 = B_ * T_ * (H_ / 4);
    for (int u = blockIdx.x * 256 + threadIdx.x; u < n4; u += stride) {
        const int row = u >> 6;
        const int c4 = (u & 63) << 2;
        const float2 a = ml[row];
        const float2 bb = ml[B_ * T_ + row];
        const float mx = fmaxf(a.x, bb.x);
        const float w0 = __expf(a.x - mx);
        const float w1 = __expf(bb.x - mx);
        const float inv = 1.f / (a.y * w0 + bb.y * w1);
        f32x4 o0 = *(const f32x4*)(Opart + (size_t)row * H_ + c4);
        f32x4 o1 = *(const f32x4*)(Opart + (size_t)(B_ * T_) * H_ +
                                   (size_t)row * H_ + c4);
        f32x4 ov;
#pragma unroll
        for (int e = 0; e < 4; ++e) ov[e] = (o0[e] * w0 + o1[e] * w1) * inv;
        *(f32x4*)(out + (size_t)row * H_ + c4) = ov;
    }
}

// ---------------------------------------------------------------------------
extern "C" void kernel_launch(void* const* d_in, const int* in_sizes, int n_in,
                              void* d_out, int out_size, void* d_ws, size_t ws_size,
                              hipStream_t stream) {
    const float* x  = (const float*)d_in[0];
    const float* Wq = (const float*)d_in[1];
    const float* bq = (const float*)d_in[2];
    const float* Wk = (const float*)d_in[3];
    const float* bk = (const float*)d_in[4];
    const float* Wv = (const float*)d_in[5];
    const float* bv = (const float*)d_in[6];
    float* out = (float*)d_out;

    char* ws = (char*)d_ws;
    unsigned short* Wt = (unsigned short*)ws;                    // 1.5 MiB @0
    float2* ml         = (float2*)(ws + 1536u * 1024u);          // 512 KiB @1.5M
    unsigned short* Qb = (unsigned short*)(ws + (2u  << 20));    // 16 MiB
    unsigned short* Kb = (unsigned short*)(ws + (18u << 20));    // 16 MiB
    unsigned short* Vt = (unsigned short*)(ws + (34u << 20));    // 16 MiB
    unsigned short* xb = (unsigned short*)(ws + (50u << 20));    // 64 MiB
    float* Opart       = (float*)(ws + (50u << 20));             // reuses xb (dead after qkv)

    hipLaunchKernelGGL(xconv, dim3(2048), dim3(256), 0, stream, x, xb);
    hipLaunchKernelGGL(wconv, dim3((3 * C_ * H_ + 255) / 256), dim3(256), 0, stream,
                       Wq, Wk, Wv, Wt);
    hipLaunchKernelGGL(qkv_gemm, dim3(T_ * B_ / 128, 3), dim3(512), 0, stream,
                       xb, Wt, bq, bk, bv, Qb, Kb, Vt);
    hipLaunchKernelGGL(attn, dim3(512), dim3(256), 0, stream,
                       Qb, Kb, Vt, Opart, ml);
    hipLaunchKernelGGL(combine, dim3(2048), dim3(256), 0, stream,
                       Opart, ml, out);
}